// Round 21
// baseline (266.956 us; speedup 1.0000x reference)
//
#include <hip/hip_runtime.h>
#include <hip/hip_bf16.h>

// GCN 2-layer forward on MI355X — round 21 = round-20 (best, 224.8us) + ONE
// change: gemm1 processes TWO independent rows per thread. r13's buf[16]
// failed because all loads fed one chain (full vmcnt drain before FMA);
// two rows give two independent load->FMA chains that interleave, doubling
// per-thread outstanding bytes (64->128B). No LDS; W1 via s_load; named regs.
// Inputs: x[N,512] f32, edge_index[2,E] int32, edge_weight[E] f32,
//         W1[512,16], b1[16], W2[16,10], b2[10]
// Outputs (concat): log_softmax(logits)[N,10], x1[N,16]

#define NF1 16   // hidden
#define NF2 10   // classes
#define FIN 512
#define EPB 8192 // edges per coarse block (256 thr * 32)
#define SK  2    // gemm1 split-K factor

typedef unsigned long long ull;
typedef unsigned short us;

// bf16 pack/unpack (round-to-nearest-even; data has no NaN)
__device__ __forceinline__ us f2bf(float f) {
    union { float f; unsigned u; } v; v.f = f;
    unsigned r = v.u + 0x7FFFu + ((v.u >> 16) & 1u);
    return (us)(r >> 16);
}
__device__ __forceinline__ float bf2f(us h) {
    union { unsigned u; float f; } v; v.u = ((unsigned)h) << 16;
    return v.f;
}
// 15-bit positive-float weight decode: bits[30:16] stored, sign=0
__device__ __forceinline__ float w15f(unsigned e) {
    union { unsigned u; float f; } v; v.u = (e >> 17) << 16;
    return v.f;
}

// ---------- A: coarse count (col>>9) into per-block histograms ----------
__global__ __launch_bounds__(256) void coarse_count_kernel(const int* __restrict__ col,
                                                           int* __restrict__ blkhist,
                                                           int E, int NB, int NBLK) {
    __shared__ int lh[256];
    int t = threadIdx.x;
    lh[t] = 0;
    __syncthreads();
    int base = blockIdx.x * EPB;
    int cnt = min(EPB, E - base);
    for (int i = t; i < cnt; i += 256)
        atomicAdd(&lh[col[base + i] >> 9], 1);
    __syncthreads();
    if (t < NB) blkhist[t * NBLK + blockIdx.x] = lh[t];
}

// ---------- B1: per-bucket exclusive scan over blocks (parallel) ----------
__global__ __launch_bounds__(512) void bucket_scan_kernel(int* __restrict__ blkhist,
                                                          int* __restrict__ btot,
                                                          int NBLK) {
    __shared__ int s[512];
    int t = threadIdx.x;
    int* p = blkhist + (size_t)blockIdx.x * NBLK;
    int carry = 0;
    for (int base = 0; base < NBLK; base += 512) {
        int idx = base + t;
        int v = (idx < NBLK) ? p[idx] : 0;
        s[t] = v;
        __syncthreads();
        for (int off = 1; off < 512; off <<= 1) {
            int u = (t >= off) ? s[t - off] : 0;
            __syncthreads();
            s[t] += u;
            __syncthreads();
        }
        if (idx < NBLK) p[idx] = s[t] - v + carry;
        carry += s[511];
        __syncthreads();
    }
    if (t == 0) btot[blockIdx.x] = carry;
}

// ---------- B2: scan bucket totals -> bbase ----------
__global__ __launch_bounds__(256) void base_scan_kernel(const int* __restrict__ btot,
                                                        int* __restrict__ bbase,
                                                        int* __restrict__ rowptr,
                                                        int NB, int E, int N) {
    __shared__ int s[256];
    int t = threadIdx.x;
    int v = (t < NB) ? btot[t] : 0;
    s[t] = v;
    __syncthreads();
    for (int off = 1; off < 256; off <<= 1) {
        int u = (t >= off) ? s[t - off] : 0;
        __syncthreads();
        s[t] += u;
        __syncthreads();
    }
    if (t < NB) bbase[t] = s[t] - v;
    if (t == 0) { bbase[NB] = E; rowptr[N] = E; }
}

// ---------- C: coarse scatter into bucket-ordered pool ----------
// pool entry: hi32 = (c9<<20)|row, lo32 = weight bits (f32)
__global__ __launch_bounds__(256) void coarse_scatter_kernel(const int* __restrict__ row,
                                                             const int* __restrict__ col,
                                                             const float* __restrict__ ew,
                                                             const int* __restrict__ blkhist,
                                                             const int* __restrict__ bbase,
                                                             ull* __restrict__ pool,
                                                             int E, int NB, int NBLK) {
    __shared__ int cur[256];
    int t = threadIdx.x;
    if (t < NB) cur[t] = blkhist[t * NBLK + blockIdx.x] + bbase[t];
    __syncthreads();
    int base = blockIdx.x * EPB;
    int cnt = min(EPB, E - base);
    for (int i = t; i < cnt; i += 256) {
        int e = base + i;
        int c = col[e], r = row[e];
        float w = ew[e];
        int b = c >> 9, c9 = c & 511;
        int pos = atomicAdd(&cur[b], 1);
        pool[pos] = ((ull)((((unsigned)c9) << 20) | (unsigned)r) << 32) | (ull)__float_as_uint(w);
    }
}

// ---------- D: fine sort within bucket -> compressed CSR, rowptr, dinv ----------
__global__ __launch_bounds__(1024) void fine_sort_kernel(const ull* __restrict__ pool,
                                                         const int* __restrict__ bbase,
                                                         unsigned* __restrict__ csr,
                                                         int* __restrict__ rowptr,
                                                         float* __restrict__ dinv, int N) {
    __shared__ int hist[512];
    __shared__ float wsum[512];
    __shared__ int cur[512];
    int t = threadIdx.x;
    int b = blockIdx.x;
    int bb = bbase[b], be = bbase[b + 1];
    int Ki = be - bb;
    if (t < 512) { hist[t] = 0; wsum[t] = 0.0f; }
    __syncthreads();
    // pass 1: hist + wsum, x4-batched loads
    int i = t;
    for (; i + 3 * 1024 < Ki; i += 4 * 1024) {
        ull p0 = pool[bb + i];
        ull p1 = pool[bb + i + 1024];
        ull p2 = pool[bb + i + 2048];
        ull p3 = pool[bb + i + 3072];
        unsigned h0 = (unsigned)(p0 >> 32), h1 = (unsigned)(p1 >> 32);
        unsigned h2 = (unsigned)(p2 >> 32), h3 = (unsigned)(p3 >> 32);
        atomicAdd(&hist[(h0 >> 20) & 511], 1);
        atomicAdd(&wsum[(h0 >> 20) & 511], __uint_as_float((unsigned)p0));
        atomicAdd(&hist[(h1 >> 20) & 511], 1);
        atomicAdd(&wsum[(h1 >> 20) & 511], __uint_as_float((unsigned)p1));
        atomicAdd(&hist[(h2 >> 20) & 511], 1);
        atomicAdd(&wsum[(h2 >> 20) & 511], __uint_as_float((unsigned)p2));
        atomicAdd(&hist[(h3 >> 20) & 511], 1);
        atomicAdd(&wsum[(h3 >> 20) & 511], __uint_as_float((unsigned)p3));
    }
    for (; i < Ki; i += 1024) {
        ull p = pool[bb + i];
        unsigned hi = (unsigned)(p >> 32);
        int c9 = (hi >> 20) & 511;
        atomicAdd(&hist[c9], 1);
        atomicAdd(&wsum[c9], __uint_as_float((unsigned)p));
    }
    __syncthreads();
    int own = (t < 512) ? hist[t] : 0;
    if (t < 512) cur[t] = own;
    __syncthreads();
    for (int off = 1; off < 512; off <<= 1) {
        int v = (t >= off && t < 512) ? cur[t - off] : 0;
        __syncthreads();
        if (t < 512) cur[t] += v;
        __syncthreads();
    }
    int excl = (t < 512) ? (cur[t] - own) : 0;
    if (t < 512) cur[t] = excl;
    int c = (b << 9) + t;
    if (t < 512 && c < N) {
        rowptr[c] = bb + excl;
        dinv[c] = rsqrtf(1.0f + wsum[t]);       // deg = self(1) + sum(w)
    }
    __syncthreads();
    // pass 2: place, x4-batched loads
    i = t;
    for (; i + 3 * 1024 < Ki; i += 4 * 1024) {
        ull p0 = pool[bb + i];
        ull p1 = pool[bb + i + 1024];
        ull p2 = pool[bb + i + 2048];
        ull p3 = pool[bb + i + 3072];
#pragma unroll
        for (int j = 0; j < 4; j++) {
            ull p = (j == 0) ? p0 : (j == 1) ? p1 : (j == 2) ? p2 : p3;
            unsigned hi = (unsigned)(p >> 32);
            int c9 = (hi >> 20) & 511;
            unsigned r = hi & 0xFFFFFu;
            unsigned lo = (unsigned)p;
            unsigned w15 = (lo + 0x8000u) >> 16;
            int k = atomicAdd(&cur[c9], 1);
            csr[bb + k] = (w15 << 17) | r;
        }
    }
    for (; i < Ki; i += 1024) {
        ull p = pool[bb + i];
        unsigned hi = (unsigned)(p >> 32);
        int c9 = (hi >> 20) & 511;
        unsigned r = hi & 0xFFFFFu;
        unsigned lo = (unsigned)p;
        unsigned w15 = (lo + 0x8000u) >> 16;
        int k = atomicAdd(&cur[c9], 1);
        csr[bb + k] = (w15 << 17) | r;
    }
}

// ---------- GEMM1 (split-K=2, TWO rows/thread, full-line loads) ----------
__device__ __forceinline__ void fma16(float av, const float* __restrict__ wrow,
                                      float* __restrict__ acc) {
#pragma unroll
    for (int f = 0; f < NF1; f++) acc[f] = fmaf(av, wrow[f], acc[f]);
}

__global__ __launch_bounds__(256) void gemm1_kernel(const float* __restrict__ x,
                                                    const float* __restrict__ W1,
                                                    float* __restrict__ part,
                                                    int N, int nbRow) {
    int b = blockIdx.x;
    int q = (b >= nbRow) ? 1 : 0;      // K-half
    int rb = b - q * nbRow;
    int row0 = rb * 512 + threadIdx.x; // rows row0 and row0+256
    int row1 = row0 + 256;
    int row0c = min(row0, N - 1);      // clamp: loads unconditional, stores guarded
    int row1c = min(row1, N - 1);
    const int k0 = q * (FIN / SK);     // 256 per half

    float acc0[NF1], acc1[NF1];
#pragma unroll
    for (int f = 0; f < NF1; f++) { acc0[f] = 0.0f; acc1[f] = 0.0f; }

    const float* xr0 = x + (size_t)row0c * FIN + k0;
    const float* xr1 = x + (size_t)row1c * FIN + k0;
    const float* wp  = W1 + (size_t)k0 * NF1;

#pragma unroll 2
    for (int k = 0; k < FIN / SK; k += 16) {
        const float4* xp0 = reinterpret_cast<const float4*>(xr0 + k);
        const float4* xp1 = reinterpret_cast<const float4*>(xr1 + k);
        // 8 independent loads in flight (two chains)
        float4 a0 = xp0[0], a1 = xp0[1], a2 = xp0[2], a3 = xp0[3];
        float4 c0 = xp1[0], c1 = xp1[1], c2 = xp1[2], c3 = xp1[3];
        const float* wk = wp + (size_t)k * NF1;
        fma16(a0.x, wk + 0 * NF1, acc0);  fma16(c0.x, wk + 0 * NF1, acc1);
        fma16(a0.y, wk + 1 * NF1, acc0);  fma16(c0.y, wk + 1 * NF1, acc1);
        fma16(a0.z, wk + 2 * NF1, acc0);  fma16(c0.z, wk + 2 * NF1, acc1);
        fma16(a0.w, wk + 3 * NF1, acc0);  fma16(c0.w, wk + 3 * NF1, acc1);
        fma16(a1.x, wk + 4 * NF1, acc0);  fma16(c1.x, wk + 4 * NF1, acc1);
        fma16(a1.y, wk + 5 * NF1, acc0);  fma16(c1.y, wk + 5 * NF1, acc1);
        fma16(a1.z, wk + 6 * NF1, acc0);  fma16(c1.z, wk + 6 * NF1, acc1);
        fma16(a1.w, wk + 7 * NF1, acc0);  fma16(c1.w, wk + 7 * NF1, acc1);
        fma16(a2.x, wk + 8 * NF1, acc0);  fma16(c2.x, wk + 8 * NF1, acc1);
        fma16(a2.y, wk + 9 * NF1, acc0);  fma16(c2.y, wk + 9 * NF1, acc1);
        fma16(a2.z, wk + 10 * NF1, acc0); fma16(c2.z, wk + 10 * NF1, acc1);
        fma16(a2.w, wk + 11 * NF1, acc0); fma16(c2.w, wk + 11 * NF1, acc1);
        fma16(a3.x, wk + 12 * NF1, acc0); fma16(c3.x, wk + 12 * NF1, acc1);
        fma16(a3.y, wk + 13 * NF1, acc0); fma16(c3.y, wk + 13 * NF1, acc1);
        fma16(a3.z, wk + 14 * NF1, acc0); fma16(c3.z, wk + 14 * NF1, acc1);
        fma16(a3.w, wk + 15 * NF1, acc0); fma16(c3.w, wk + 15 * NF1, acc1);
    }

    if (row0 < N) {
        float* pp = part + ((size_t)q * N + row0) * NF1;
#pragma unroll
        for (int qq = 0; qq < 4; qq++) {
            float4 o = make_float4(acc0[4 * qq], acc0[4 * qq + 1], acc0[4 * qq + 2], acc0[4 * qq + 3]);
            *reinterpret_cast<float4*>(pp + 4 * qq) = o;
        }
    }
    if (row1 < N) {
        float* pp = part + ((size_t)q * N + row1) * NF1;
#pragma unroll
        for (int qq = 0; qq < 4; qq++) {
            float4 o = make_float4(acc1[4 * qq], acc1[4 * qq + 1], acc1[4 * qq + 2], acc1[4 * qq + 3]);
            *reinterpret_cast<float4*>(pp + 4 * qq) = o;
        }
    }
}

// ---------- combine split-K partials, fold dinv, pack bf16: hs16 = bf16(dinv*(Σp)) ----------
__global__ __launch_bounds__(256) void combine_scale_kernel(const float* __restrict__ part,
                                                            const float* __restrict__ dinv,
                                                            us* __restrict__ hs16, int N) {
    int i4 = blockIdx.x * 256 + threadIdx.x;     // 4-float chunk index
    int total = N * NF1 / 4;
    if (i4 >= total) return;
    int rowIdx = i4 >> 2;                        // 4 chunks per row
    const float4* p0 = reinterpret_cast<const float4*>(part);
    const float4* p1 = reinterpret_cast<const float4*>(part + (size_t)N * NF1);
    float4 a = p0[i4], b = p1[i4];
    float d = dinv[rowIdx];
    ushort4 u;
    u.x = f2bf(d * (a.x + b.x));
    u.y = f2bf(d * (a.y + b.y));
    u.z = f2bf(d * (a.z + b.z));
    u.w = f2bf(d * (a.w + b.w));
    reinterpret_cast<ushort4*>(hs16)[i4] = u;
}

// ---------- gather layer 1 (x8 unroll) + FUSED gemm2 ----------
// x1[c] = b1 + di*( sum w_i*hs[r_i] + hs[c] );  hh = bf16(di * relu(x1)@W2)
__global__ __launch_bounds__(256) void gather1_gemm2_kernel(const unsigned* __restrict__ csr,
                                                            const int* __restrict__ rowptr,
                                                            const float* __restrict__ dinv,
                                                            const us* __restrict__ hs16,
                                                            const float* __restrict__ b1,
                                                            const float* __restrict__ W2,
                                                            float* __restrict__ x1,
                                                            us* __restrict__ hh16, int N) {
    int t = blockIdx.x * 256 + threadIdx.x;
    int node = t >> 4, f = t & 15;
    if (node >= N) return;
    int s = rowptr[node], e = rowptr[node + 1];
    float di = dinv[node];
    float acc = bf2f(hs16[(size_t)node * NF1 + f]);   // self-loop: hs[c]
    int i = s;
    for (; i + 7 < e; i += 8) {
        unsigned e0 = csr[i],     e1 = csr[i + 1], e2 = csr[i + 2], e3 = csr[i + 3];
        unsigned e4 = csr[i + 4], e5 = csr[i + 5], e6 = csr[i + 6], e7 = csr[i + 7];
        float h0 = bf2f(hs16[(size_t)(e0 & 0x1FFFF) * NF1 + f]);
        float h1 = bf2f(hs16[(size_t)(e1 & 0x1FFFF) * NF1 + f]);
        float h2 = bf2f(hs16[(size_t)(e2 & 0x1FFFF) * NF1 + f]);
        float h3 = bf2f(hs16[(size_t)(e3 & 0x1FFFF) * NF1 + f]);
        float h4 = bf2f(hs16[(size_t)(e4 & 0x1FFFF) * NF1 + f]);
        float h5 = bf2f(hs16[(size_t)(e5 & 0x1FFFF) * NF1 + f]);
        float h6 = bf2f(hs16[(size_t)(e6 & 0x1FFFF) * NF1 + f]);
        float h7 = bf2f(hs16[(size_t)(e7 & 0x1FFFF) * NF1 + f]);
        acc += w15f(e0) * h0;
        acc += w15f(e1) * h1;
        acc += w15f(e2) * h2;
        acc += w15f(e3) * h3;
        acc += w15f(e4) * h4;
        acc += w15f(e5) * h5;
        acc += w15f(e6) * h6;
        acc += w15f(e7) * h7;
    }
    for (; i < e; i++) {
        unsigned e0 = csr[i];
        acc += w15f(e0) * bf2f(hs16[(size_t)(e0 & 0x1FFFF) * NF1 + f]);
    }
    float x1v = b1[f] + di * acc;
    x1[(size_t)node * NF1 + f] = x1v;

    // fused gemm2: each 16-lane group holds the full x1 row
    float xr = fmaxf(x1v, 0.0f);
    float hhv = 0.0f;
#pragma unroll
    for (int c = 0; c < NF2; c++) {
        float v = xr * W2[f * NF2 + c];
#pragma unroll
        for (int off = 1; off < 16; off <<= 1) v += __shfl_xor(v, off, 16);
        if (f == c) hhv = v;
    }
    if (f < NF2) hh16[(size_t)node * NF2 + f] = f2bf(di * hhv);
}

// ---------- gather layer 2 (x8 unroll) + fused log-softmax ----------
__global__ __launch_bounds__(256) void gather2_lsm_kernel(const unsigned* __restrict__ csr,
                                                          const int* __restrict__ rowptr,
                                                          const float* __restrict__ dinv,
                                                          const us* __restrict__ hh16,
                                                          const float* __restrict__ b2,
                                                          float* __restrict__ out, int N) {
    int t = blockIdx.x * 256 + threadIdx.x;
    int node = t >> 4, f = t & 15;
    bool act = (node < N) && (f < NF2);
    float acc = 0.0f;
    if (node < N) {
        int s = rowptr[node], e = rowptr[node + 1];
        float di = dinv[node];
        acc = act ? bf2f(hh16[(size_t)node * NF2 + f]) : 0.0f;   // self-loop
        int i = s;
        if (f < NF2) {
            for (; i + 7 < e; i += 8) {
                unsigned e0 = csr[i],     e1 = csr[i + 1], e2 = csr[i + 2], e3 = csr[i + 3];
                unsigned e4 = csr[i + 4], e5 = csr[i + 5], e6 = csr[i + 6], e7 = csr[i + 7];
                float h0 = bf2f(hh16[(size_t)(e0 & 0x1FFFF) * NF2 + f]);
                float h1 = bf2f(hh16[(size_t)(e1 & 0x1FFFF) * NF2 + f]);
                float h2 = bf2f(hh16[(size_t)(e2 & 0x1FFFF) * NF2 + f]);
                float h3 = bf2f(hh16[(size_t)(e3 & 0x1FFFF) * NF2 + f]);
                float h4 = bf2f(hh16[(size_t)(e4 & 0x1FFFF) * NF2 + f]);
                float h5 = bf2f(hh16[(size_t)(e5 & 0x1FFFF) * NF2 + f]);
                float h6 = bf2f(hh16[(size_t)(e6 & 0x1FFFF) * NF2 + f]);
                float h7 = bf2f(hh16[(size_t)(e7 & 0x1FFFF) * NF2 + f]);
                acc += w15f(e0) * h0;
                acc += w15f(e1) * h1;
                acc += w15f(e2) * h2;
                acc += w15f(e3) * h3;
                acc += w15f(e4) * h4;
                acc += w15f(e5) * h5;
                acc += w15f(e6) * h6;
                acc += w15f(e7) * h7;
            }
            for (; i < e; i++) {
                unsigned e0 = csr[i];
                acc += w15f(e0) * bf2f(hh16[(size_t)(e0 & 0x1FFFF) * NF2 + f]);
            }
        }
        acc = b2[f] + di * acc;  // garbage in lanes f>=10, masked below
    }
    // log-softmax across the 16-lane group (10 active lanes)
    float m = act ? acc : -INFINITY;
#pragma unroll
    for (int off = 1; off < 16; off <<= 1) m = fmaxf(m, __shfl_xor(m, off, 16));
    float p = act ? expf(acc - m) : 0.0f;
    float ssum = p;
#pragma unroll
    for (int off = 1; off < 16; off <<= 1) ssum += __shfl_xor(ssum, off, 16);
    if (act) out[(size_t)node * NF2 + f] = acc - m - logf(ssum);
}

extern "C" void kernel_launch(void* const* d_in, const int* in_sizes, int n_in,
                              void* d_out, int out_size, void* d_ws, size_t ws_size,
                              hipStream_t stream) {
    const float* x  = (const float*)d_in[0];
    const int*   ei = (const int*)d_in[1];
    const float* ew = (const float*)d_in[2];
    const float* W1 = (const float*)d_in[3];
    const float* b1 = (const float*)d_in[4];
    const float* W2 = (const float*)d_in[5];
    const float* b2 = (const float*)d_in[6];

    const int E = in_sizes[2];           // 3,200,000
    const int N = in_sizes[0] / FIN;     // 100,000
    const int* row = ei;
    const int* col = ei + E;

    const int NB   = (N + 511) >> 9;     // coarse buckets (196)
    const int NBLK = (E + EPB - 1) / EPB;

    float* out    = (float*)d_out;
    float* logits = out;                        // [N,10]
    float* x1     = out + (size_t)N * NF2;      // [N,16]

    char* ws = (char*)d_ws;
    size_t off = 0;
    auto alloc = [&](size_t bytes) { void* p = ws + off; off += (bytes + 255) / 256 * 256; return p; };
    ull*      pool    = (ull*)     alloc((size_t)E * 8);
    unsigned* csr     = (unsigned*)alloc((size_t)E * 4);          // compressed entries
    float*    part    = (float*)   alloc((size_t)SK * N * NF1 * 4);
    us*       hs16    = (us*)      alloc((size_t)N * NF1 * 2);    // bf16 dinv*(x@W1)
    us*       hh16    = (us*)      alloc((size_t)N * NF2 * 2 + 64);
    float*    dinv    = (float*)   alloc((size_t)N * 4);
    int*      rowptr  = (int*)     alloc((size_t)(N + 1) * 4);
    int*      blkhist = (int*)     alloc((size_t)NB * NBLK * 4);
    int*      btot    = (int*)     alloc((size_t)NB * 4);
    int*      bbase   = (int*)     alloc((size_t)(NB + 1) * 4);
    (void)ws_size; (void)n_in; (void)out_size;

    dim3 blk(256);
    int g16    = (N + 15) / 16;
    int nbRow2 = (N + 511) / 512;        // gemm1 row-blocks per K-half (512 rows each)

    // build compressed CSR (no global atomics)
    coarse_count_kernel<<<NBLK, blk, 0, stream>>>(col, blkhist, E, NB, NBLK);
    bucket_scan_kernel<<<NB, dim3(512), 0, stream>>>(blkhist, btot, NBLK);
    base_scan_kernel<<<1, blk, 0, stream>>>(btot, bbase, rowptr, NB, E, N);
    coarse_scatter_kernel<<<NBLK, blk, 0, stream>>>(row, col, ew, blkhist, bbase, pool, E, NB, NBLK);
    fine_sort_kernel<<<NB, dim3(1024), 0, stream>>>(pool, bbase, csr, rowptr, dinv, N);

    // layer 1 (+ fused layer-2 GEMM)
    gemm1_kernel<<<SK * nbRow2, blk, 0, stream>>>(x, W1, part, N, nbRow2);
    combine_scale_kernel<<<(N * NF1 / 4 + 255) / 256, blk, 0, stream>>>(part, dinv, hs16, N);
    gather1_gemm2_kernel<<<g16, blk, 0, stream>>>(csr, rowptr, dinv, hs16, b1, W2, x1, hh16, N);

    // layer 2 aggregation + log-softmax
    gather2_lsm_kernel<<<g16, blk, 0, stream>>>(csr, rowptr, dinv, hh16, b2, logits, N);
}

// Round 22
// 225.756 us; speedup vs baseline: 1.1825x; 1.1825x over previous
//
#include <hip/hip_runtime.h>
#include <hip/hip_bf16.h>

// GCN 2-layer forward on MI355X — round 22 = round-20 EXACTLY (best, 224.8us).
// Round-21's two-row gemm1 regressed (VGPR occupancy step) and is reverted —
// the 7th and final gemm1 experiment. This configuration: zero global atomics,
// coarse+fine LDS counting sort, compressed 4B CSR (15-bit weight + 17-bit row),
// bf16 hs/hh tables (L2-resident), x8 MLP-unrolled gathers, gemm2 fused into
// gather1, log-softmax fused into gather2, split-K=2 gemm1 with full-line loads.
// Inputs: x[N,512] f32, edge_index[2,E] int32, edge_weight[E] f32,
//         W1[512,16], b1[16], W2[16,10], b2[10]
// Outputs (concat): log_softmax(logits)[N,10], x1[N,16]

#define NF1 16   // hidden
#define NF2 10   // classes
#define FIN 512
#define EPB 8192 // edges per coarse block (256 thr * 32)
#define SK  2    // gemm1 split-K factor

typedef unsigned long long ull;
typedef unsigned short us;

// bf16 pack/unpack (round-to-nearest-even; data has no NaN)
__device__ __forceinline__ us f2bf(float f) {
    union { float f; unsigned u; } v; v.f = f;
    unsigned r = v.u + 0x7FFFu + ((v.u >> 16) & 1u);
    return (us)(r >> 16);
}
__device__ __forceinline__ float bf2f(us h) {
    union { unsigned u; float f; } v; v.u = ((unsigned)h) << 16;
    return v.f;
}
// 15-bit positive-float weight decode: bits[30:16] stored, sign=0
__device__ __forceinline__ float w15f(unsigned e) {
    union { unsigned u; float f; } v; v.u = (e >> 17) << 16;
    return v.f;
}

// ---------- A: coarse count (col>>9) into per-block histograms ----------
__global__ __launch_bounds__(256) void coarse_count_kernel(const int* __restrict__ col,
                                                           int* __restrict__ blkhist,
                                                           int E, int NB, int NBLK) {
    __shared__ int lh[256];
    int t = threadIdx.x;
    lh[t] = 0;
    __syncthreads();
    int base = blockIdx.x * EPB;
    int cnt = min(EPB, E - base);
    for (int i = t; i < cnt; i += 256)
        atomicAdd(&lh[col[base + i] >> 9], 1);
    __syncthreads();
    if (t < NB) blkhist[t * NBLK + blockIdx.x] = lh[t];
}

// ---------- B1: per-bucket exclusive scan over blocks (parallel) ----------
__global__ __launch_bounds__(512) void bucket_scan_kernel(int* __restrict__ blkhist,
                                                          int* __restrict__ btot,
                                                          int NBLK) {
    __shared__ int s[512];
    int t = threadIdx.x;
    int* p = blkhist + (size_t)blockIdx.x * NBLK;
    int carry = 0;
    for (int base = 0; base < NBLK; base += 512) {
        int idx = base + t;
        int v = (idx < NBLK) ? p[idx] : 0;
        s[t] = v;
        __syncthreads();
        for (int off = 1; off < 512; off <<= 1) {
            int u = (t >= off) ? s[t - off] : 0;
            __syncthreads();
            s[t] += u;
            __syncthreads();
        }
        if (idx < NBLK) p[idx] = s[t] - v + carry;
        carry += s[511];
        __syncthreads();
    }
    if (t == 0) btot[blockIdx.x] = carry;
}

// ---------- B2: scan bucket totals -> bbase ----------
__global__ __launch_bounds__(256) void base_scan_kernel(const int* __restrict__ btot,
                                                        int* __restrict__ bbase,
                                                        int* __restrict__ rowptr,
                                                        int NB, int E, int N) {
    __shared__ int s[256];
    int t = threadIdx.x;
    int v = (t < NB) ? btot[t] : 0;
    s[t] = v;
    __syncthreads();
    for (int off = 1; off < 256; off <<= 1) {
        int u = (t >= off) ? s[t - off] : 0;
        __syncthreads();
        s[t] += u;
        __syncthreads();
    }
    if (t < NB) bbase[t] = s[t] - v;
    if (t == 0) { bbase[NB] = E; rowptr[N] = E; }
}

// ---------- C: coarse scatter into bucket-ordered pool ----------
// pool entry: hi32 = (c9<<20)|row, lo32 = weight bits (f32)
__global__ __launch_bounds__(256) void coarse_scatter_kernel(const int* __restrict__ row,
                                                             const int* __restrict__ col,
                                                             const float* __restrict__ ew,
                                                             const int* __restrict__ blkhist,
                                                             const int* __restrict__ bbase,
                                                             ull* __restrict__ pool,
                                                             int E, int NB, int NBLK) {
    __shared__ int cur[256];
    int t = threadIdx.x;
    if (t < NB) cur[t] = blkhist[t * NBLK + blockIdx.x] + bbase[t];
    __syncthreads();
    int base = blockIdx.x * EPB;
    int cnt = min(EPB, E - base);
    for (int i = t; i < cnt; i += 256) {
        int e = base + i;
        int c = col[e], r = row[e];
        float w = ew[e];
        int b = c >> 9, c9 = c & 511;
        int pos = atomicAdd(&cur[b], 1);
        pool[pos] = ((ull)((((unsigned)c9) << 20) | (unsigned)r) << 32) | (ull)__float_as_uint(w);
    }
}

// ---------- D: fine sort within bucket -> compressed CSR, rowptr, dinv ----------
__global__ __launch_bounds__(1024) void fine_sort_kernel(const ull* __restrict__ pool,
                                                         const int* __restrict__ bbase,
                                                         unsigned* __restrict__ csr,
                                                         int* __restrict__ rowptr,
                                                         float* __restrict__ dinv, int N) {
    __shared__ int hist[512];
    __shared__ float wsum[512];
    __shared__ int cur[512];
    int t = threadIdx.x;
    int b = blockIdx.x;
    int bb = bbase[b], be = bbase[b + 1];
    int Ki = be - bb;
    if (t < 512) { hist[t] = 0; wsum[t] = 0.0f; }
    __syncthreads();
    // pass 1: hist + wsum, x4-batched loads
    int i = t;
    for (; i + 3 * 1024 < Ki; i += 4 * 1024) {
        ull p0 = pool[bb + i];
        ull p1 = pool[bb + i + 1024];
        ull p2 = pool[bb + i + 2048];
        ull p3 = pool[bb + i + 3072];
        unsigned h0 = (unsigned)(p0 >> 32), h1 = (unsigned)(p1 >> 32);
        unsigned h2 = (unsigned)(p2 >> 32), h3 = (unsigned)(p3 >> 32);
        atomicAdd(&hist[(h0 >> 20) & 511], 1);
        atomicAdd(&wsum[(h0 >> 20) & 511], __uint_as_float((unsigned)p0));
        atomicAdd(&hist[(h1 >> 20) & 511], 1);
        atomicAdd(&wsum[(h1 >> 20) & 511], __uint_as_float((unsigned)p1));
        atomicAdd(&hist[(h2 >> 20) & 511], 1);
        atomicAdd(&wsum[(h2 >> 20) & 511], __uint_as_float((unsigned)p2));
        atomicAdd(&hist[(h3 >> 20) & 511], 1);
        atomicAdd(&wsum[(h3 >> 20) & 511], __uint_as_float((unsigned)p3));
    }
    for (; i < Ki; i += 1024) {
        ull p = pool[bb + i];
        unsigned hi = (unsigned)(p >> 32);
        int c9 = (hi >> 20) & 511;
        atomicAdd(&hist[c9], 1);
        atomicAdd(&wsum[c9], __uint_as_float((unsigned)p));
    }
    __syncthreads();
    int own = (t < 512) ? hist[t] : 0;
    if (t < 512) cur[t] = own;
    __syncthreads();
    for (int off = 1; off < 512; off <<= 1) {
        int v = (t >= off && t < 512) ? cur[t - off] : 0;
        __syncthreads();
        if (t < 512) cur[t] += v;
        __syncthreads();
    }
    int excl = (t < 512) ? (cur[t] - own) : 0;
    if (t < 512) cur[t] = excl;
    int c = (b << 9) + t;
    if (t < 512 && c < N) {
        rowptr[c] = bb + excl;
        dinv[c] = rsqrtf(1.0f + wsum[t]);       // deg = self(1) + sum(w)
    }
    __syncthreads();
    // pass 2: place, x4-batched loads
    i = t;
    for (; i + 3 * 1024 < Ki; i += 4 * 1024) {
        ull p0 = pool[bb + i];
        ull p1 = pool[bb + i + 1024];
        ull p2 = pool[bb + i + 2048];
        ull p3 = pool[bb + i + 3072];
#pragma unroll
        for (int j = 0; j < 4; j++) {
            ull p = (j == 0) ? p0 : (j == 1) ? p1 : (j == 2) ? p2 : p3;
            unsigned hi = (unsigned)(p >> 32);
            int c9 = (hi >> 20) & 511;
            unsigned r = hi & 0xFFFFFu;
            unsigned lo = (unsigned)p;
            unsigned w15 = (lo + 0x8000u) >> 16;
            int k = atomicAdd(&cur[c9], 1);
            csr[bb + k] = (w15 << 17) | r;
        }
    }
    for (; i < Ki; i += 1024) {
        ull p = pool[bb + i];
        unsigned hi = (unsigned)(p >> 32);
        int c9 = (hi >> 20) & 511;
        unsigned r = hi & 0xFFFFFu;
        unsigned lo = (unsigned)p;
        unsigned w15 = (lo + 0x8000u) >> 16;
        int k = atomicAdd(&cur[c9], 1);
        csr[bb + k] = (w15 << 17) | r;
    }
}

// ---------- GEMM1 (split-K=2, no LDS, full-line loads): part[q][row][f] ----------
__device__ __forceinline__ void fma16(float av, const float* __restrict__ wrow,
                                      float* __restrict__ acc) {
#pragma unroll
    for (int f = 0; f < NF1; f++) acc[f] = fmaf(av, wrow[f], acc[f]);
}

__global__ __launch_bounds__(256) void gemm1_kernel(const float* __restrict__ x,
                                                    const float* __restrict__ W1,
                                                    float* __restrict__ part,
                                                    int N, int nbRow) {
    int b = blockIdx.x;
    int q = (b >= nbRow) ? 1 : 0;      // K-half
    int rb = b - q * nbRow;
    int row = rb * 256 + threadIdx.x;
    if (row >= N) return;
    const int k0 = q * (FIN / SK);     // 256 per half

    float acc[NF1];
#pragma unroll
    for (int f = 0; f < NF1; f++) acc[f] = 0.0f;

    const float* xr = x + (size_t)row * FIN + k0;
    const float* wp = W1 + (size_t)k0 * NF1;

#pragma unroll 2
    for (int k = 0; k < FIN / SK; k += 16) {
        const float4* xp = reinterpret_cast<const float4*>(xr + k);
        float4 a0 = xp[0];
        float4 a1 = xp[1];
        float4 a2 = xp[2];
        float4 a3 = xp[3];
        const float* wk = wp + (size_t)k * NF1;
        fma16(a0.x, wk + 0 * NF1, acc);
        fma16(a0.y, wk + 1 * NF1, acc);
        fma16(a0.z, wk + 2 * NF1, acc);
        fma16(a0.w, wk + 3 * NF1, acc);
        fma16(a1.x, wk + 4 * NF1, acc);
        fma16(a1.y, wk + 5 * NF1, acc);
        fma16(a1.z, wk + 6 * NF1, acc);
        fma16(a1.w, wk + 7 * NF1, acc);
        fma16(a2.x, wk + 8 * NF1, acc);
        fma16(a2.y, wk + 9 * NF1, acc);
        fma16(a2.z, wk + 10 * NF1, acc);
        fma16(a2.w, wk + 11 * NF1, acc);
        fma16(a3.x, wk + 12 * NF1, acc);
        fma16(a3.y, wk + 13 * NF1, acc);
        fma16(a3.z, wk + 14 * NF1, acc);
        fma16(a3.w, wk + 15 * NF1, acc);
    }

    float* pp = part + ((size_t)q * N + row) * NF1;
#pragma unroll
    for (int qq = 0; qq < 4; qq++) {
        float4 o = make_float4(acc[4 * qq], acc[4 * qq + 1], acc[4 * qq + 2], acc[4 * qq + 3]);
        *reinterpret_cast<float4*>(pp + 4 * qq) = o;
    }
}

// ---------- combine split-K partials, fold dinv, pack bf16: hs16 = bf16(dinv*(Σp)) ----------
__global__ __launch_bounds__(256) void combine_scale_kernel(const float* __restrict__ part,
                                                            const float* __restrict__ dinv,
                                                            us* __restrict__ hs16, int N) {
    int i4 = blockIdx.x * 256 + threadIdx.x;     // 4-float chunk index
    int total = N * NF1 / 4;
    if (i4 >= total) return;
    int rowIdx = i4 >> 2;                        // 4 chunks per row
    const float4* p0 = reinterpret_cast<const float4*>(part);
    const float4* p1 = reinterpret_cast<const float4*>(part + (size_t)N * NF1);
    float4 a = p0[i4], b = p1[i4];
    float d = dinv[rowIdx];
    ushort4 u;
    u.x = f2bf(d * (a.x + b.x));
    u.y = f2bf(d * (a.y + b.y));
    u.z = f2bf(d * (a.z + b.z));
    u.w = f2bf(d * (a.w + b.w));
    reinterpret_cast<ushort4*>(hs16)[i4] = u;
}

// ---------- gather layer 1 (x8 unroll) + FUSED gemm2 ----------
// x1[c] = b1 + di*( sum w_i*hs[r_i] + hs[c] );  hh = bf16(di * relu(x1)@W2)
__global__ __launch_bounds__(256) void gather1_gemm2_kernel(const unsigned* __restrict__ csr,
                                                            const int* __restrict__ rowptr,
                                                            const float* __restrict__ dinv,
                                                            const us* __restrict__ hs16,
                                                            const float* __restrict__ b1,
                                                            const float* __restrict__ W2,
                                                            float* __restrict__ x1,
                                                            us* __restrict__ hh16, int N) {
    int t = blockIdx.x * 256 + threadIdx.x;
    int node = t >> 4, f = t & 15;
    if (node >= N) return;
    int s = rowptr[node], e = rowptr[node + 1];
    float di = dinv[node];
    float acc = bf2f(hs16[(size_t)node * NF1 + f]);   // self-loop: hs[c]
    int i = s;
    for (; i + 7 < e; i += 8) {
        unsigned e0 = csr[i],     e1 = csr[i + 1], e2 = csr[i + 2], e3 = csr[i + 3];
        unsigned e4 = csr[i + 4], e5 = csr[i + 5], e6 = csr[i + 6], e7 = csr[i + 7];
        float h0 = bf2f(hs16[(size_t)(e0 & 0x1FFFF) * NF1 + f]);
        float h1 = bf2f(hs16[(size_t)(e1 & 0x1FFFF) * NF1 + f]);
        float h2 = bf2f(hs16[(size_t)(e2 & 0x1FFFF) * NF1 + f]);
        float h3 = bf2f(hs16[(size_t)(e3 & 0x1FFFF) * NF1 + f]);
        float h4 = bf2f(hs16[(size_t)(e4 & 0x1FFFF) * NF1 + f]);
        float h5 = bf2f(hs16[(size_t)(e5 & 0x1FFFF) * NF1 + f]);
        float h6 = bf2f(hs16[(size_t)(e6 & 0x1FFFF) * NF1 + f]);
        float h7 = bf2f(hs16[(size_t)(e7 & 0x1FFFF) * NF1 + f]);
        acc += w15f(e0) * h0;
        acc += w15f(e1) * h1;
        acc += w15f(e2) * h2;
        acc += w15f(e3) * h3;
        acc += w15f(e4) * h4;
        acc += w15f(e5) * h5;
        acc += w15f(e6) * h6;
        acc += w15f(e7) * h7;
    }
    for (; i < e; i++) {
        unsigned e0 = csr[i];
        acc += w15f(e0) * bf2f(hs16[(size_t)(e0 & 0x1FFFF) * NF1 + f]);
    }
    float x1v = b1[f] + di * acc;
    x1[(size_t)node * NF1 + f] = x1v;

    // fused gemm2: each 16-lane group holds the full x1 row
    float xr = fmaxf(x1v, 0.0f);
    float hhv = 0.0f;
#pragma unroll
    for (int c = 0; c < NF2; c++) {
        float v = xr * W2[f * NF2 + c];
#pragma unroll
        for (int off = 1; off < 16; off <<= 1) v += __shfl_xor(v, off, 16);
        if (f == c) hhv = v;
    }
    if (f < NF2) hh16[(size_t)node * NF2 + f] = f2bf(di * hhv);
}

// ---------- gather layer 2 (x8 unroll) + fused log-softmax ----------
__global__ __launch_bounds__(256) void gather2_lsm_kernel(const unsigned* __restrict__ csr,
                                                          const int* __restrict__ rowptr,
                                                          const float* __restrict__ dinv,
                                                          const us* __restrict__ hh16,
                                                          const float* __restrict__ b2,
                                                          float* __restrict__ out, int N) {
    int t = blockIdx.x * 256 + threadIdx.x;
    int node = t >> 4, f = t & 15;
    bool act = (node < N) && (f < NF2);
    float acc = 0.0f;
    if (node < N) {
        int s = rowptr[node], e = rowptr[node + 1];
        float di = dinv[node];
        acc = act ? bf2f(hh16[(size_t)node * NF2 + f]) : 0.0f;   // self-loop
        int i = s;
        if (f < NF2) {
            for (; i + 7 < e; i += 8) {
                unsigned e0 = csr[i],     e1 = csr[i + 1], e2 = csr[i + 2], e3 = csr[i + 3];
                unsigned e4 = csr[i + 4], e5 = csr[i + 5], e6 = csr[i + 6], e7 = csr[i + 7];
                float h0 = bf2f(hh16[(size_t)(e0 & 0x1FFFF) * NF2 + f]);
                float h1 = bf2f(hh16[(size_t)(e1 & 0x1FFFF) * NF2 + f]);
                float h2 = bf2f(hh16[(size_t)(e2 & 0x1FFFF) * NF2 + f]);
                float h3 = bf2f(hh16[(size_t)(e3 & 0x1FFFF) * NF2 + f]);
                float h4 = bf2f(hh16[(size_t)(e4 & 0x1FFFF) * NF2 + f]);
                float h5 = bf2f(hh16[(size_t)(e5 & 0x1FFFF) * NF2 + f]);
                float h6 = bf2f(hh16[(size_t)(e6 & 0x1FFFF) * NF2 + f]);
                float h7 = bf2f(hh16[(size_t)(e7 & 0x1FFFF) * NF2 + f]);
                acc += w15f(e0) * h0;
                acc += w15f(e1) * h1;
                acc += w15f(e2) * h2;
                acc += w15f(e3) * h3;
                acc += w15f(e4) * h4;
                acc += w15f(e5) * h5;
                acc += w15f(e6) * h6;
                acc += w15f(e7) * h7;
            }
            for (; i < e; i++) {
                unsigned e0 = csr[i];
                acc += w15f(e0) * bf2f(hh16[(size_t)(e0 & 0x1FFFF) * NF2 + f]);
            }
        }
        acc = b2[f] + di * acc;  // garbage in lanes f>=10, masked below
    }
    // log-softmax across the 16-lane group (10 active lanes)
    float m = act ? acc : -INFINITY;
#pragma unroll
    for (int off = 1; off < 16; off <<= 1) m = fmaxf(m, __shfl_xor(m, off, 16));
    float p = act ? expf(acc - m) : 0.0f;
    float ssum = p;
#pragma unroll
    for (int off = 1; off < 16; off <<= 1) ssum += __shfl_xor(ssum, off, 16);
    if (act) out[(size_t)node * NF2 + f] = acc - m - logf(ssum);
}

extern "C" void kernel_launch(void* const* d_in, const int* in_sizes, int n_in,
                              void* d_out, int out_size, void* d_ws, size_t ws_size,
                              hipStream_t stream) {
    const float* x  = (const float*)d_in[0];
    const int*   ei = (const int*)d_in[1];
    const float* ew = (const float*)d_in[2];
    const float* W1 = (const float*)d_in[3];
    const float* b1 = (const float*)d_in[4];
    const float* W2 = (const float*)d_in[5];
    const float* b2 = (const float*)d_in[6];

    const int E = in_sizes[2];           // 3,200,000
    const int N = in_sizes[0] / FIN;     // 100,000
    const int* row = ei;
    const int* col = ei + E;

    const int NB   = (N + 511) >> 9;     // coarse buckets (196)
    const int NBLK = (E + EPB - 1) / EPB;

    float* out    = (float*)d_out;
    float* logits = out;                        // [N,10]
    float* x1     = out + (size_t)N * NF2;      // [N,16]

    char* ws = (char*)d_ws;
    size_t off = 0;
    auto alloc = [&](size_t bytes) { void* p = ws + off; off += (bytes + 255) / 256 * 256; return p; };
    ull*      pool    = (ull*)     alloc((size_t)E * 8);
    unsigned* csr     = (unsigned*)alloc((size_t)E * 4);          // compressed entries
    float*    part    = (float*)   alloc((size_t)SK * N * NF1 * 4);
    us*       hs16    = (us*)      alloc((size_t)N * NF1 * 2);    // bf16 dinv*(x@W1)
    us*       hh16    = (us*)      alloc((size_t)N * NF2 * 2 + 64);
    float*    dinv    = (float*)   alloc((size_t)N * 4);
    int*      rowptr  = (int*)     alloc((size_t)(N + 1) * 4);
    int*      blkhist = (int*)     alloc((size_t)NB * NBLK * 4);
    int*      btot    = (int*)     alloc((size_t)NB * 4);
    int*      bbase   = (int*)     alloc((size_t)(NB + 1) * 4);
    (void)ws_size; (void)n_in; (void)out_size;

    dim3 blk(256);
    int g16   = (N + 15) / 16;
    int nbRow = (N + 255) / 256;         // gemm1 row-blocks per K-half

    // build compressed CSR (no global atomics)
    coarse_count_kernel<<<NBLK, blk, 0, stream>>>(col, blkhist, E, NB, NBLK);
    bucket_scan_kernel<<<NB, dim3(512), 0, stream>>>(blkhist, btot, NBLK);
    base_scan_kernel<<<1, blk, 0, stream>>>(btot, bbase, rowptr, NB, E, N);
    coarse_scatter_kernel<<<NBLK, blk, 0, stream>>>(row, col, ew, blkhist, bbase, pool, E, NB, NBLK);
    fine_sort_kernel<<<NB, dim3(1024), 0, stream>>>(pool, bbase, csr, rowptr, dinv, N);

    // layer 1 (+ fused layer-2 GEMM)
    gemm1_kernel<<<SK * nbRow, blk, 0, stream>>>(x, W1, part, N, nbRow);
    combine_scale_kernel<<<(N * NF1 / 4 + 255) / 256, blk, 0, stream>>>(part, dinv, hs16, N);
    gather1_gemm2_kernel<<<g16, blk, 0, stream>>>(csr, rowptr, dinv, hs16, b1, W2, x1, hh16, N);

    // layer 2 aggregation + log-softmax
    gather2_lsm_kernel<<<g16, blk, 0, stream>>>(csr, rowptr, dinv, hh16, b2, logits, N);
}